// Round 2
// baseline (38.905 us; speedup 1.0000x reference)
//
#include <hip/hip_runtime.h>

// Problem constants (from reference)
#define B_IMG 8
#define C_IN  16
#define COUT  64
#define H0    36
#define H1    6
#define NB    6
#define NNODE 43            // 36 + 6 + 1 nodes per channel
// OH = OW = 16; 256 pixels per image; output [8][64][16][16]

// d_ws layout:
//   floats [COUT*NNODE*64]  : per-(channel,node) sigmoid'd table, delta form
//                             [ lo[r]=sig(w[r]) r<32 | dd[r]=sig(w[r+32])-sig(w[r]) ]
//   ints   [COUT*H0*12]     : per-(channel,layer0-node) gather meta, 6 x int2 {off, kh|kw<<8}
#define TBL_FLOATS (COUT*NNODE*64)

typedef float f32x2 __attribute__((ext_vector_type(2)));

__device__ __forceinline__ float sigf(float v) { return 1.0f / (1.0f + __expf(-v)); }

__global__ __launch_bounds__(256) void setup_kernel(
    const float* __restrict__ table0,
    const float* __restrict__ table1,
    const float* __restrict__ table2,
    const int*   __restrict__ idx0,
    float*       __restrict__ wsf)
{
    int id = blockIdx.x * 256 + threadIdx.x;
    const int NTBL = COUT * NNODE * 32;          // one thread per (t,node,k<32)
    if (id < NTBL) {
        int k    = id & 31;
        int tn   = id >> 5;
        int node = tn % NNODE;
        int t    = tn / NNODE;
        const float* src;
        if (node < H0)         src = table0 + ((size_t)t*H0 + node) * 64;
        else if (node < H0+H1) src = table1 + ((size_t)t*H1 + (node - H0)) * 64;
        else                   src = table2 + (size_t)t * 64;
        float lo = sigf(src[k]);
        float hi = sigf(src[k + 32]);
        wsf[(size_t)tn*64 + k]      = lo;
        wsf[(size_t)tn*64 + 32 + k] = hi - lo;
    } else {
        int m = id - NTBL;                        // one thread per (t, n<36, i<6)
        if (m >= COUT * H0 * NB) return;
        int i  = m % NB;
        int nn = (m / NB) % H0;
        int t  = m / (NB * H0);
        int*  meta = (int*)(wsf + TBL_FLOATS);
        int   raw  = idx0[(size_t)t*(H0*NB) + nn*NB + i];
        int c   = raw / 25;
        int rem = raw - c * 25;
        int kh  = rem / 5;
        int kw  = rem - kh * 5;
        // offset into image slice (may be negative at borders; masked at use)
        meta[((size_t)t*H0 + nn)*12 + i*2 + 0] = c*1024 + (kh - 2)*32 + (kw - 2);
        meta[((size_t)t*H0 + nn)*12 + i*2 + 1] = kh | (kw << 8);
    }
}

// 6-bit multilinear interp from delta-form table (global, wave-uniform broadcast).
// g[0] contracts bit5 (MSB) ... g[5] contracts bit0, matching the reference.
__device__ __forceinline__ float lut_contract(const float* __restrict__ tb, const float g[NB]) {
    const float4* t4 = (const float4*)tb;
    f32x2 v[16];
    const float g0 = g[0];
#pragma unroll
    for (int q = 0; q < 8; ++q) {
        float4 lo4 = t4[q];
        float4 dd4 = t4[q + 8];
        v[2*q+0] = (f32x2){lo4.x, lo4.y} + (f32x2){dd4.x, dd4.y} * g0;   // pk_fma
        v[2*q+1] = (f32x2){lo4.z, lo4.w} + (f32x2){dd4.z, dd4.w} * g0;
    }
#pragma unroll
    for (int i = 1; i < 5; ++i) {
        const int vh = 16 >> i;
        const float gi = g[i];
#pragma unroll
        for (int r = 0; r < vh; ++r)
            v[r] += (v[r + vh] - v[r]) * gi;                              // pk_sub+pk_fma
    }
    return v[0].x + (v[0].y - v[0].x) * g[5];
}

__global__ __launch_bounds__(256) void lutconv_kernel(
    const float* __restrict__ x,
    const int*   __restrict__ idx1,
    const int*   __restrict__ idx2,
    const float* __restrict__ wsf,
    float*       __restrict__ out)
{
    __shared__ int   idx1L[H1*NB];      // remapped to h0 slots
    __shared__ int   idx2L[NB];
    __shared__ int   slotOf[H0];        // used-flag, then slot id
    __shared__ int   usedList[H0];
    __shared__ int   usedCnt;
    __shared__ float h0s[H0*256];       // [slot][tid] — conflict-free
    __shared__ float h1s[H1*256];

    const int tid = threadIdx.x;
    const int t   = blockIdx.x & 63;    // channel
    const int img = blockIdx.x >> 6;    // image

    // ---- prune: find layer-0 nodes actually referenced by idx1 ----
    if (tid < H0) slotOf[tid] = 0;
    __syncthreads();
    if (tid < H1*NB) {
        int raw = idx1[(size_t)t*(H1*NB) + tid];
        idx1L[tid] = raw;               // raw for now; remapped below
        slotOf[raw] = 1;                // benign race: all write 1
    }
    if (tid < NB) idx2L[tid] = idx2[(size_t)t*NB + tid];
    __syncthreads();
    if (tid == 0) {
        int cnt = 0;
        for (int n = 0; n < H0; ++n)
            if (slotOf[n]) { usedList[cnt] = n; slotOf[n] = cnt; ++cnt; }
        usedCnt = cnt;
    }
    __syncthreads();
    if (tid < H1*NB) idx1L[tid] = slotOf[idx1L[tid]];
    __syncthreads();

    // ---- per-thread pixel ----
    const int oh  = tid >> 4, ow = tid & 15;
    const int oh2 = oh * 2,  ow2 = ow * 2;
    const int base = img*(C_IN*32*32) + oh2*32 + ow2;
    // validity bitmasks over kh/kw in [0,5)
    int hm = 0, wm = 0;
#pragma unroll
    for (int k = 0; k < 5; ++k) {
        hm |= (((unsigned)(oh2 + k - 2) < 32u) ? 1 : 0) << k;
        wm |= (((unsigned)(ow2 + k - 2) < 32u) ? 1 : 0) << k;
    }

    const float* tblT  = wsf + (size_t)t * NNODE * 64;
    const int*   metaT = (const int*)(wsf + TBL_FLOATS) + (size_t)t * H0 * 12;

    // ---- layer 0: only used nodes ----
    const int nU = usedCnt;
    for (int s = 0; s < nU; ++s) {
        const int n = __builtin_amdgcn_readfirstlane(usedList[s]);
        const int4* mp = (const int4*)(metaT + n*12);
        int4 m01 = mp[0], m23 = mp[1], m45 = mp[2];
        float g[NB];
        {
            int offs[NB] = {m01.x, m01.z, m23.x, m23.z, m45.x, m45.z};
            int pks [NB] = {m01.y, m01.w, m23.y, m23.w, m45.y, m45.w};
#pragma unroll
            for (int i = 0; i < NB; ++i) {
                int kh = pks[i] & 255, kw = pks[i] >> 8;
                bool ok = (((hm >> kh) & (wm >> kw)) & 1) != 0;
                float v = x[ok ? (base + offs[i]) : 0];
                g[i] = ok ? v : 0.0f;
            }
        }
        h0s[s*256 + tid] = lut_contract(tblT + n*64, g);
    }

    // ---- layer 1 (no barrier: each thread reads only its own column) ----
    for (int n = 0; n < H1; ++n) {
        float g[NB];
#pragma unroll
        for (int i = 0; i < NB; ++i) g[i] = h0s[idx1L[n*NB + i]*256 + tid];
        h1s[n*256 + tid] = lut_contract(tblT + (H0 + n)*64, g);
    }

    // ---- layer 2 ----
    {
        float g[NB];
#pragma unroll
        for (int i = 0; i < NB; ++i) g[i] = h1s[idx2L[i]*256 + tid];
        out[((size_t)img*COUT + t)*256 + tid] = lut_contract(tblT + (H0 + H1)*64, g);
    }
}

extern "C" void kernel_launch(void* const* d_in, const int* in_sizes, int n_in,
                              void* d_out, int out_size, void* d_ws, size_t ws_size,
                              hipStream_t stream) {
    const float* x      = (const float*)d_in[0];
    const int*   idx0   = (const int*)  d_in[1];
    const float* table0 = (const float*)d_in[2];
    const int*   idx1   = (const int*)  d_in[3];
    const float* table1 = (const float*)d_in[4];
    const int*   idx2   = (const int*)  d_in[5];
    const float* table2 = (const float*)d_in[6];
    float* out = (float*)d_out;
    float* wsf = (float*)d_ws;

    const int setup_items = COUT*NNODE*32 + COUT*H0*NB;
    setup_kernel<<<(setup_items + 255)/256, 256, 0, stream>>>(table0, table1, table2, idx0, wsf);
    lutconv_kernel<<<COUT * B_IMG, 256, 0, stream>>>(x, idx1, idx2, wsf, out);
}